// Round 1
// baseline (469.902 us; speedup 1.0000x reference)
//
#include <hip/hip_runtime.h>
#include <hip/hip_bf16.h>

typedef __bf16 bf16;
typedef __bf16 bf16x8 __attribute__((ext_vector_type(8)));
typedef __bf16 bf16x4 __attribute__((ext_vector_type(4)));
typedef float f32x4 __attribute__((ext_vector_type(4)));

#define NBIG 7168
#define KBIG 2048

__device__ __forceinline__ float sigmoid_f(float x) { return 1.0f / (1.0f + __expf(-x)); }
__device__ __forceinline__ float tanh_f(float x) { return 1.0f - 2.0f / (__expf(2.0f * x) + 1.0f); }

__device__ __forceinline__ void gload_lds16(const bf16* g, bf16* lds) {
  __builtin_amdgcn_global_load_lds(
      (const __attribute__((address_space(1))) unsigned int*)g,
      (__attribute__((address_space(3))) unsigned int*)lds,
      16, 0, 0);
}

// ---------------- prep kernels ----------------

// A_big[m][0:1024] = x[m], A_big[m][1024:2048] = h[m], bf16
__global__ __launch_bounds__(256) void build_A(const float* __restrict__ x,
                                               const float* __restrict__ h,
                                               bf16* __restrict__ A) {
  const int i4 = blockIdx.x * 256 + threadIdx.x;  // < 8192*2048/4
  const int o = i4 * 4;
  const int m = o >> 11;
  const int c = o & 2047;
  const float4 v = (c < 1024) ? *(const float4*)&x[(size_t)m * 1024 + c]
                              : *(const float4*)&h[(size_t)m * 1024 + (c - 1024)];
  bf16x4 b;
  b[0] = (bf16)v.x; b[1] = (bf16)v.y; b[2] = (bf16)v.z; b[3] = (bf16)v.w;
  *(bf16x4*)&A[(size_t)o] = b;
}

// WG rows: [0,5120): gate g = n>>10 -> [W_g | U_g]; [5120,6144): a1_w (2048 wide);
// [6144,7168): [0 | r1_w]
__global__ __launch_bounds__(256) void build_WG(
    const float* __restrict__ Wi, const float* __restrict__ Wf, const float* __restrict__ Wo,
    const float* __restrict__ Wc, const float* __restrict__ Ws,
    const float* __restrict__ Ui, const float* __restrict__ Uf, const float* __restrict__ Uo,
    const float* __restrict__ Uc, const float* __restrict__ Us,
    const float* __restrict__ a1w, const float* __restrict__ r1w, bf16* __restrict__ WG) {
  const int i4 = blockIdx.x * 256 + threadIdx.x;  // < 7168*2048/4
  const int o = i4 * 4;
  const int n = o >> 11;
  const int c = o & 2047;
  const int g = n >> 10;
  const int r = n & 1023;
  float4 v;
  if (g < 5) {
    const float* Wp = g == 0 ? Wi : g == 1 ? Wf : g == 2 ? Wo : g == 3 ? Wc : Ws;
    const float* Up = g == 0 ? Ui : g == 1 ? Uf : g == 2 ? Uo : g == 3 ? Uc : Us;
    v = (c < 1024) ? *(const float4*)&Wp[(size_t)r * 1024 + c]
                   : *(const float4*)&Up[(size_t)r * 1024 + (c - 1024)];
  } else if (g == 5) {
    v = *(const float4*)&a1w[(size_t)r * 2048 + c];
  } else {
    if (c < 1024) { v.x = 0.f; v.y = 0.f; v.z = 0.f; v.w = 0.f; }
    else v = *(const float4*)&r1w[(size_t)r * 1024 + (c - 1024)];
  }
  bf16x4 b;
  b[0] = (bf16)v.x; b[1] = (bf16)v.y; b[2] = (bf16)v.z; b[3] = (bf16)v.w;
  *(bf16x4*)&WG[(size_t)o] = b;
}

__global__ __launch_bounds__(256) void build_bias(
    const float* __restrict__ Wib, const float* __restrict__ Wfb, const float* __restrict__ Wob,
    const float* __restrict__ Wcb, const float* __restrict__ Wsb,
    const float* __restrict__ Uib, const float* __restrict__ Ufb, const float* __restrict__ Uob,
    const float* __restrict__ Ucb, const float* __restrict__ Usb,
    const float* __restrict__ a1b, const float* __restrict__ r1b, float* __restrict__ bias) {
  const int n = blockIdx.x * 256 + threadIdx.x;
  if (n >= NBIG) return;
  const int g = n >> 10, r = n & 1023;
  float v;
  if (g < 5) {
    const float* Wb = g == 0 ? Wib : g == 1 ? Wfb : g == 2 ? Wob : g == 3 ? Wcb : Wsb;
    const float* Ub = g == 0 ? Uib : g == 1 ? Ufb : g == 2 ? Uob : g == 3 ? Ucb : Usb;
    v = Wb[r] + Ub[r];
  } else if (g == 5) v = a1b[r];
  else v = r1b[r];
  bias[n] = v;
}

__global__ __launch_bounds__(256) void f2b(const float* __restrict__ s, bf16* __restrict__ d,
                                           int n4) {
  const int i = blockIdx.x * 256 + threadIdx.x;
  if (i >= n4) return;
  const float4 v = *(const float4*)&s[(size_t)i * 4];
  bf16x4 b;
  b[0] = (bf16)v.x; b[1] = (bf16)v.y; b[2] = (bf16)v.z; b[3] = (bf16)v.w;
  *(bf16x4*)&d[(size_t)i * 4] = b;
}

// ---------------- GEMM: C = act(A @ W^T + bias) ----------------
// A [M x K] row-major stride lda (bf16); W [N x K] row-major (bf16).
// 128x128 tile, BK=32, 4 waves each own 64x64 (4x4 frags of 16x16x32).
// act_mode 0: per-column regions (n>>10: 0,1,2,4=sigmoid, 3=tanh, 5,6=relu)
// act_mode 1: relu; act_mode 2: none.
__global__ __launch_bounds__(256) void gemm_bt(const bf16* __restrict__ A, int lda,
                                               const bf16* __restrict__ W, int K,
                                               const float* __restrict__ bias,
                                               bf16* __restrict__ C, int ldc, int act_mode) {
  __shared__ __align__(16) bf16 As[128 * 32];
  __shared__ __align__(16) bf16 Bs[128 * 32];

  const int tid = threadIdx.x;
  const int lane = tid & 63;
  const int wv = tid >> 6;
  const int bm = blockIdx.x * 128;
  const int bn = blockIdx.y * 128;
  const int wr = wv >> 1, wc = wv & 1;

  // staging: wave wv, issue j covers rows (j*64 + wv*16 .. +16), lane -> row + l/4, col (l&3)*8
  const int srow = wv * 16 + (lane >> 2);
  const int scol = (lane & 3) * 8;
  const bf16* ag0 = A + (size_t)(bm + srow) * lda + scol;
  const bf16* ag1 = ag0 + (size_t)64 * lda;
  const bf16* bg0 = W + (size_t)(bn + srow) * K + scol;
  const bf16* bg1 = bg0 + (size_t)64 * K;
  bf16* const al0 = &As[(wv * 16) * 32];
  bf16* const al1 = &As[(64 + wv * 16) * 32];
  bf16* const bl0 = &Bs[(wv * 16) * 32];
  bf16* const bl1 = &Bs[(64 + wv * 16) * 32];

  f32x4 acc[4][4] = {};

  const int k0 = (lane >> 4) * 8;
  const int fr = lane & 15;
  const int niter = K >> 5;
  for (int kt = 0; kt < niter; ++kt) {
    __syncthreads();  // protect LDS from previous iteration's readers
    gload_lds16(ag0, al0);
    gload_lds16(ag1, al1);
    gload_lds16(bg0, bl0);
    gload_lds16(bg1, bl1);
    ag0 += 32; ag1 += 32; bg0 += 32; bg1 += 32;
    __syncthreads();  // drains vmcnt -> tile resident

    bf16x8 af[4], bfv[4];
#pragma unroll
    for (int f = 0; f < 4; ++f) {
      af[f] = *(const bf16x8*)&As[(wr * 64 + f * 16 + fr) * 32 + k0];
      bfv[f] = *(const bf16x8*)&Bs[(wc * 64 + f * 16 + fr) * 32 + k0];
    }
#pragma unroll
    for (int i = 0; i < 4; ++i)
#pragma unroll
      for (int j = 0; j < 4; ++j)
        acc[i][j] = __builtin_amdgcn_mfma_f32_16x16x32_bf16(af[i], bfv[j], acc[i][j], 0, 0, 0);
  }

  // epilogue: C/D layout col = lane&15, row = (lane>>4)*4 + r  [m89]
  const int rbase = (lane >> 4) * 4;
#pragma unroll
  for (int j = 0; j < 4; ++j) {
    const int n = bn + wc * 64 + j * 16 + fr;
    const float bv = bias[n];
    const int g = (act_mode == 0) ? (n >> 10) : (act_mode == 1 ? 100 : 101);
#pragma unroll
    for (int i = 0; i < 4; ++i) {
      const size_t mrow = (size_t)(bm + wr * 64 + i * 16 + rbase);
#pragma unroll
      for (int r = 0; r < 4; ++r) {
        float v = acc[i][j][r] + bv;
        if (g == 3) v = tanh_f(v);
        else if (g < 5) v = sigmoid_f(v);
        else if (g < 7 || g == 100) v = fmaxf(v, 0.0f);
        C[(mrow + r) * (size_t)ldc + n] = (bf16)v;
      }
    }
  }
}

// ---------------- alpha: sigmoid(relu(a1) . a2_w + a2_b), one wave per row ----------------
__global__ __launch_bounds__(256) void alpha_k(const bf16* __restrict__ G,
                                               const float* __restrict__ a2w,
                                               const float* __restrict__ a2b,
                                               float* __restrict__ alpha) {
  const int m = blockIdx.x * 4 + (threadIdx.x >> 6);
  const int lane = threadIdx.x & 63;
  const bf16* row = G + (size_t)m * NBIG + 5120 + lane * 16;
  const bf16x8 v0 = *(const bf16x8*)row;
  const bf16x8 v1 = *(const bf16x8*)(row + 8);
  const float* w = a2w + lane * 16;
  float s = 0.f;
#pragma unroll
  for (int e = 0; e < 8; ++e) s += (float)v0[e] * w[e] + (float)v1[e] * w[8 + e];
#pragma unroll
  for (int off = 32; off > 0; off >>= 1) s += __shfl_down(s, off, 64);
  if (lane == 0) alpha[m] = sigmoid_f(s + a2b[0]);
}

// ---------------- final elementwise ----------------
__global__ __launch_bounds__(256) void final_k(const bf16* __restrict__ G,
                                               const bf16* __restrict__ R3,
                                               const float* __restrict__ c_prev,
                                               const float* __restrict__ alpha,
                                               float* __restrict__ out) {
  const int idx = blockIdx.x * 256 + threadIdx.x;  // < 8192*1024/8
  const int o = idx * 8;
  const int m = o >> 10;
  const int c = o & 1023;
  const size_t gb = (size_t)m * NBIG;
  const bf16x8 iv = *(const bf16x8*)&G[gb + c];
  const bf16x8 fv = *(const bf16x8*)&G[gb + 1024 + c];
  const bf16x8 ov = *(const bf16x8*)&G[gb + 2048 + c];
  const bf16x8 cv = *(const bf16x8*)&G[gb + 3072 + c];
  const bf16x8 sv = *(const bf16x8*)&G[gb + 4096 + c];
  const bf16x8 rv = *(const bf16x8*)&R3[(size_t)m * 1024 + c];
  const float al = alpha[m];
  const float* cp = &c_prev[(size_t)m * 1024 + c];
  float hbuf[8], cbuf[8];
#pragma unroll
  for (int e = 0; e < 8; ++e) {
    const float ct = (float)fv[e] * cp[e] + (float)iv[e] * (float)cv[e] * (float)sv[e] * al
                     + (float)rv[e];
    cbuf[e] = ct;
    hbuf[e] = (float)ov[e] * tanh_f(ct);
  }
  float* oh = out + (size_t)m * 1024 + c;
  float* oc = out + (size_t)8192 * 1024 + (size_t)m * 1024 + c;
#pragma unroll
  for (int e = 0; e < 8; ++e) { oh[e] = hbuf[e]; oc[e] = cbuf[e]; }
}

// ---------------- launch ----------------
extern "C" void kernel_launch(void* const* d_in, const int* in_sizes, int n_in,
                              void* d_out, int out_size, void* d_ws, size_t ws_size,
                              hipStream_t stream) {
  const float* x      = (const float*)d_in[0];
  const float* h_prev = (const float*)d_in[1];
  const float* c_prev = (const float*)d_in[2];
  const float* Wi_w = (const float*)d_in[3];  const float* Wi_b = (const float*)d_in[4];
  const float* Wf_w = (const float*)d_in[5];  const float* Wf_b = (const float*)d_in[6];
  const float* Wo_w = (const float*)d_in[7];  const float* Wo_b = (const float*)d_in[8];
  const float* Wc_w = (const float*)d_in[9];  const float* Wc_b = (const float*)d_in[10];
  const float* Ws_w = (const float*)d_in[11]; const float* Ws_b = (const float*)d_in[12];
  const float* Ui_w = (const float*)d_in[13]; const float* Ui_b = (const float*)d_in[14];
  const float* Uf_w = (const float*)d_in[15]; const float* Uf_b = (const float*)d_in[16];
  const float* Uo_w = (const float*)d_in[17]; const float* Uo_b = (const float*)d_in[18];
  const float* Uc_w = (const float*)d_in[19]; const float* Uc_b = (const float*)d_in[20];
  const float* Us_w = (const float*)d_in[21]; const float* Us_b = (const float*)d_in[22];
  const float* a1_w = (const float*)d_in[23]; const float* a1_b = (const float*)d_in[24];
  const float* a2_w = (const float*)d_in[25]; const float* a2_b = (const float*)d_in[26];
  const float* r1_w = (const float*)d_in[27]; const float* r1_b = (const float*)d_in[28];
  const float* r2_w = (const float*)d_in[29]; const float* r2_b = (const float*)d_in[30];
  const float* r3_w = (const float*)d_in[31]; const float* r3_b = (const float*)d_in[32];

  char* ws = (char*)d_ws;
  size_t off = 0;
  auto alloc = [&](size_t bytes) -> void* {
    void* p = ws + off;
    off += (bytes + 255) & ~(size_t)255;
    return p;
  };
  bf16* A_big    = (bf16*)alloc((size_t)8192 * 2048 * 2);
  bf16* WG       = (bf16*)alloc((size_t)7168 * 2048 * 2);
  float* bias_bg = (float*)alloc((size_t)7168 * 4);
  bf16* WR2      = (bf16*)alloc((size_t)1024 * 1024 * 2);
  bf16* WR3      = (bf16*)alloc((size_t)1024 * 1024 * 2);
  bf16* G        = (bf16*)alloc((size_t)8192 * 7168 * 2);
  bf16* R2       = (bf16*)alloc((size_t)8192 * 1024 * 2);
  bf16* R3       = (bf16*)alloc((size_t)8192 * 1024 * 2);
  float* alpha   = (float*)alloc((size_t)8192 * 4);

  build_A<<<16384, 256, 0, stream>>>(x, h_prev, A_big);
  build_WG<<<14336, 256, 0, stream>>>(Wi_w, Wf_w, Wo_w, Wc_w, Ws_w,
                                      Ui_w, Uf_w, Uo_w, Uc_w, Us_w, a1_w, r1_w, WG);
  build_bias<<<28, 256, 0, stream>>>(Wi_b, Wf_b, Wo_b, Wc_b, Ws_b,
                                     Ui_b, Uf_b, Uo_b, Uc_b, Us_b, a1_b, r1_b, bias_bg);
  f2b<<<1024, 256, 0, stream>>>(r2_w, WR2, 262144);
  f2b<<<1024, 256, 0, stream>>>(r3_w, WR3, 262144);

  // big fused GEMM: [8192 x 2048] @ [7168 x 2048]^T -> gates/a1/r1 with activations
  dim3 g1(64, 56);
  gemm_bt<<<g1, 256, 0, stream>>>(A_big, 2048, WG, 2048, bias_bg, G, NBIG, 0);

  // alpha head (depends only on GEMM1)
  alpha_k<<<2048, 256, 0, stream>>>(G, a2_w, a2_b, alpha);

  // residual chain r2 -> r3
  dim3 g2(64, 8);
  gemm_bt<<<g2, 256, 0, stream>>>(G + 6144, NBIG, WR2, 1024, r2_b, R2, 1024, 1);
  gemm_bt<<<g2, 256, 0, stream>>>(R2, 1024, WR3, 1024, r3_b, R3, 1024, 2);

  final_k<<<4096, 256, 0, stream>>>(G, R3, c_prev, alpha, (float*)d_out);
}